// Round 11
// baseline (798.516 us; speedup 1.0000x reference)
//
#include <hip/hip_runtime.h>

// ---------------------------------------------------------------------------
// Model_81990925681018 — Round 11:
// (1) conv waves 2x2 (4 m-tiles x 2 col-frags per wave): halves per-MFMA LDS
//     read demand (R10 was ds_read-throughput-bound: 16 b128 vs 32 MFMA per
//     block-iter); A-frag duplication only costs L2-resident traffic.
// (2) attn 64-col blocks: acc1 8x4->4x4 (128->64 VGPRs; was VGPR=196,
//     Occ=10.9%), grid doubled.
// ---------------------------------------------------------------------------

#define CDIV(a,b) (((a)+(b)-1)/(b))

#define B_    16
#define L_    4096
#define D_    256
#define LP_   4112      // L + 2*POFF
#define POFF  8
#define F_    100
#define A_    256
#define C_    50
#define NN_   512
#define EE_   8192
#define ADJ_  8704
#define OC_   560

#define PLANE ((size_t)B_*LP_*128)     // one branch t-plane (shorts)
#define TTS   ((size_t)B_*128*L_)      // one branch tT plane (shorts)
#define SST   ((size_t)B_*64*L_)       // one branch S (bf16 elems)
#define VPS   ((size_t)B_*64*16*112)   // one branch Vpart (floats), 16 chunks

#define WFC1_STRIDE ((size_t)9*8*8*512)   // per-branch conv1 frag stride (shorts)
#define WFRES_STRIDE ((size_t)9*4*8*512)  // per (branch,block) res frag stride
#define WFAW_STRIDE ((size_t)4*16*512)
#define WFAU_STRIDE ((size_t)8*4*512)

typedef unsigned short u16;
using short8  = __attribute__((ext_vector_type(8))) short;
using short4v = __attribute__((ext_vector_type(4))) short;
using f32x4   = __attribute__((ext_vector_type(4))) float;

__device__ __forceinline__ u16 f2b(float f){
    unsigned u = __float_as_uint(f);
    u += 0x7FFF + ((u >> 16) & 1);
    return (u16)(u >> 16);
}
__device__ __forceinline__ float b2f(u16 h){ return __uint_as_float(((unsigned)h) << 16); }

// ---------------- utility fills ----------------
__global__ void fill_i_k(int* p, int n, int v){
    int i = blockIdx.x*256 + threadIdx.x; if (i < n) p[i] = v;
}
// zero pad cols of 3 consecutive [b][LP_][128] planes
__global__ void zero_pads3_k(u16* p){
    int idx = blockIdx.x*256 + threadIdx.x;
    if (idx >= 3*B_*16*128) return;
    int ch = idx & 127; int rest = idx >> 7;
    int pc = rest & 15; rest >>= 4;
    int b = rest & 15;  int br = rest >> 4;
    int col = (pc < 8) ? pc : (4096 + pc);
    p[(size_t)br*PLANE + ((size_t)b*LP_ + col)*128 + ch] = 0;
}

// ---------------- embedding gather -> bf16 plane [b][col][256] -------------
__global__ __launch_bounds__(256) void embed1_k(const int* __restrict__ x,
                                                const float* __restrict__ emb,
                                                u16* __restrict__ hH){
    int b = blockIdx.y;
    int col = blockIdx.x*8 + (threadIdx.x >> 5);
    int cg  = (threadIdx.x & 31) * 8;
    size_t o = ((size_t)b*LP_ + col)*D_ + cg;
    int l = col - POFF;
    short8 h0;
    if (l < 0 || l >= L_){
        #pragma unroll
        for (int i = 0; i < 8; ++i) h0[i] = 0;
    } else {
        int tok = x[b*L_ + l];
        const float* s = emb + (size_t)tok*D_ + cg;
        #pragma unroll
        for (int i = 0; i < 8; ++i) h0[i] = (short)f2b(s[i]);
    }
    *(short8*)(hH + o) = h0;
}

// ---------------- weight -> MFMA A-fragment packer (single plane) ----------
__device__ __forceinline__ void pack_frag(const float* src, u16* dst,
                                          int M, int K, int kt, int nch, int MTtot, int idx){
    int i = idx & 7, lane = (idx >> 3) & 63, rest = idx >> 9;
    int mt = rest % MTtot, r2 = rest / MTtot;
    int cc = r2 % nch,  j = r2 / nch;
    int m  = mt*16 + (lane & 15);
    int ch = cc*32 + (lane >> 4)*8 + i;
    float v = (m < M && ch < K) ? src[((size_t)m*K + ch)*kt + j] : 0.f;
    dst[(size_t)rest*512 + lane*8 + i] = f2b(v);
}
__global__ void pack_conv1_k(const float* w3, const float* w5, const float* w9, u16* dst){
    int br = blockIdx.y;
    int k = (br == 0) ? 3 : (br == 1) ? 5 : 9;
    const float* s = (br == 0) ? w3 : (br == 1) ? w5 : w9;
    int idx = blockIdx.x*256 + threadIdx.x;
    if (idx < k*8*8*512) pack_frag(s, dst + (size_t)br*WFC1_STRIDE, F_, 256, k, 8, 8, idx);
}
__global__ void pack_res_k(const float* w3, const float* w5, const float* w9, u16* dst){
    int br = blockIdx.y, blk = blockIdx.z;
    int k = (br == 0) ? 3 : (br == 1) ? 5 : 9;
    const float* s = ((br == 0) ? w3 : (br == 1) ? w5 : w9) + (size_t)blk*F_*F_*k;
    int idx = blockIdx.x*256 + threadIdx.x;
    if (idx < k*4*8*512) pack_frag(s, dst + (size_t)(br*2 + blk)*WFRES_STRIDE, F_, F_, k, 4, 8, idx);
}
__global__ void pack_aw_k(const float* aw, u16* dst){
    int br = blockIdx.y;
    int idx = blockIdx.x*256 + threadIdx.x;
    if (idx < 4*16*512) pack_frag(aw + (size_t)br*A_*F_, dst + (size_t)br*WFAW_STRIDE, A_, F_, 1, 4, 16, idx);
}
__global__ void pack_au_k(const float* au, u16* dst){
    int br = blockIdx.y;
    int idx = blockIdx.x*256 + threadIdx.x;
    if (idx < 8*4*512) pack_frag(au + (size_t)br*C_*A_, dst + (size_t)br*WFAU_STRIDE, C_, A_, 1, 8, 4, idx);
}
// fin1_w[128][556] -> w1t[560][128] zero-padded
__global__ void transpose_fin1_k(const float* __restrict__ src, float* __restrict__ dst){
    int idx = blockIdx.x*256 + threadIdx.x;
    if (idx >= OC_*128) return;
    int h = idx & 127, j = idx >> 7;
    dst[idx] = (j < 556) ? src[h*556 + j] : 0.f;
}

// ---------------- conv main loop, compile-time KT, 2x2 waves ---------------
// wave (wm,wn): m-tiles wm*4..wm*4+3 (64 rows), col-frags wn*32 + {0,16}.
// Per iter: 2 ds_read_b128 + 4 A-prefetch + 8 MFMA  -> MFMA-bound.
template<int KT, int NCH>
__device__ __forceinline__ void conv_loop(
    const u16* __restrict__ inb, int CHp_in,
    const u16* __restrict__ wf,
    short* sm, int n0, int tid, int wm, int wn, int lane, int q, int lr,
    f32x4 (&acc)[4][2])
{
    constexpr int NPASS = NCH / 4;
    for (int pass = 0; pass < NPASS; ++pass){
        // ---- stage 4 chunks: 80 cols x 32 ch each ----
        #pragma unroll
        for (int s5 = 0; s5 < 5; ++s5){
            int idx = s5*256 + tid;
            int cc = idx / 320;
            int e = idx - cc*320;
            int col = e >> 2, qq = e & 3;
            *(short8*)(sm + cc*3200 + col*40 + qq*8) =
                *(const short8*)(inb + (size_t)(n0 + col)*CHp_in + (pass*4 + cc)*32 + qq*8);
        }
        __syncthreads();
        const u16* wbase = wf + ((size_t)(pass*4)*8 + wm*4)*512 + lane*8;
        const short* bbase = sm + (8 - (KT >> 1) + wn*32 + lr)*40 + q*8;
        short8 Ac[4], An[4];
        #pragma unroll
        for (int t = 0; t < 4; ++t) Ac[t] = *(const short8*)(wbase + (size_t)t*512);
        #pragma unroll
        for (int it = 0; it < KT*4; ++it){
            const int j = it >> 2, cc = it & 3;
            if (it + 1 < KT*4){
                const int jn = (it+1) >> 2, ccn = (it+1) & 3;
                const u16* fn = wbase + (size_t)(jn*NCH + ccn)*8*512;
                #pragma unroll
                for (int t = 0; t < 4; ++t) An[t] = *(const short8*)(fn + (size_t)t*512);
            }
            short8 Bv[2];
            #pragma unroll
            for (int n = 0; n < 2; ++n)
                Bv[n] = *(const short8*)(bbase + cc*3200 + (j + n*16)*40);
            #pragma unroll
            for (int t = 0; t < 4; ++t)
                #pragma unroll
                for (int n = 0; n < 2; ++n)
                    acc[t][n] = __builtin_amdgcn_mfma_f32_16x16x32_bf16(Ac[t], Bv[n], acc[t][n], 0,0,0);
            if (it + 1 < KT*4){
                #pragma unroll
                for (int t = 0; t < 4; ++t) Ac[t] = An[t];
            }
        }
        __syncthreads();
    }
}

// ---------------- MFMA shifted-GEMM conv, 64-col tile, branch-fused --------
// grid (64, B, 3). MODE 0: tanh(acc+bias)*s+beta ; MODE 1: tanh(acc*s+beta+resid)
template<int MODE, int NCH>
__global__ __launch_bounds__(256) void conv_mfma_k(
    const u16* __restrict__ in_base, int CHp_in, long in_bs,
    const u16* __restrict__ wf_base, long wf_bs,
    const float* __restrict__ bias0, const float* __restrict__ bias1,
    const float* __restrict__ bias2,
    const float* __restrict__ gamma_base, const float* __restrict__ beta_base, int layeroff,
    u16* __restrict__ out_base, u16* __restrict__ outT_base)
{
    __shared__ short sm[12800];  // staging 4 chunks x 80x40 ; epilogue 32x136
    const int tid = threadIdx.x, lane = tid & 63;
    const int w = tid >> 6, wm = w >> 1, wn = w & 1;
    const int q = lane >> 4, lr = lane & 15;
    const int n0 = blockIdx.x * 64;
    const int b  = blockIdx.y;
    const int br = blockIdx.z;
    const u16* in = in_base + (size_t)br*in_bs;
    const u16* wf = wf_base + (size_t)br*wf_bs;
    const float* bias = (MODE == 0) ? ((br == 0) ? bias0 : (br == 1) ? bias1 : bias2) : nullptr;
    const float* gamma = gamma_base + br*300 + layeroff;
    const float* beta  = beta_base  + br*300 + layeroff;
    u16* out  = out_base + (size_t)br*PLANE;
    u16* outT = outT_base ? (outT_base + (size_t)br*TTS) : nullptr;
    const u16* inb = in + (size_t)b*LP_*CHp_in;

    f32x4 acc[4][2];
    #pragma unroll
    for (int t = 0; t < 4; ++t)
        #pragma unroll
        for (int n = 0; n < 2; ++n) acc[t][n] = (f32x4){0.f,0.f,0.f,0.f};

    if (br == 0)      conv_loop<3,NCH>(inb, CHp_in, wf, sm, n0, tid, wm, wn, lane, q, lr, acc);
    else if (br == 1) conv_loop<5,NCH>(inb, CHp_in, wf, sm, n0, tid, wm, wn, lane, q, lr, acc);
    else              conv_loop<9,NCH>(inb, CHp_in, wf, sm, n0, tid, wm, wn, lane, q, lr, acc);

    // ---- epilogue: transpose to [col][128] plane via LDS, 2 passes of 32 cols
    const float BNS = 0.9999950000374997f; // 1/sqrt(1+1e-5)
    for (int p = 0; p < 2; ++p){
        if (wn == p){
            #pragma unroll
            for (int t = 0; t < 4; ++t){
                #pragma unroll
                for (int n = 0; n < 2; ++n){
                    int mbase = wm*64 + t*16 + q*4;
                    int cl = n*16 + lr;
                    int colg = n0 + p*32 + cl;
                    float rsum[4] = {0.f,0.f,0.f,0.f};
                    if (MODE == 1){
                        size_t ro = ((size_t)b*LP_ + POFF + colg)*CHp_in + mbase;
                        short4v rh = *(const short4v*)(in + ro);
                        #pragma unroll
                        for (int r = 0; r < 4; ++r) rsum[r] = b2f((u16)rh[r]);
                    }
                    short4v hv;
                    #pragma unroll
                    for (int r = 0; r < 4; ++r){
                        int mm = mbase + r;
                        float a = acc[t][n][r];
                        float v;
                        if (MODE == 0){
                            float bi=0.f, s=0.f, be=0.f;
                            if (mm < F_){ bi = bias[mm]; s = gamma[mm]*BNS; be = beta[mm]; }
                            v = tanhf(a + bi)*s + be;
                        } else {
                            float s=0.f, be=0.f;
                            if (mm < F_){ s = gamma[mm]*BNS; be = beta[mm]; }
                            v = tanhf(fmaf(a, s, be) + rsum[r]);
                        }
                        hv[r] = (short)f2b(v);
                    }
                    *(short4v*)(sm + cl*136 + mbase) = hv;
                }
            }
        }
        __syncthreads();
        for (int idx = tid; idx < 512; idx += 256){
            int col = idx >> 4, q8 = idx & 15;
            short8 vv = *(const short8*)(sm + col*136 + q8*8);
            *(short8*)(out + ((size_t)b*LP_ + POFF + n0 + p*32 + col)*128 + q8*8) = vv;
        }
        if (outT){
            int f = tid & 127, half = tid >> 7;
            u16 vals[16];
            #pragma unroll
            for (int i = 0; i < 16; ++i) vals[i] = (u16)sm[(half*16 + i)*136 + f];
            short8 v0, v1;
            #pragma unroll
            for (int i = 0; i < 8; ++i){ v0[i] = (short)vals[i]; v1[i] = (short)vals[8+i]; }
            u16* dst = outT + ((size_t)b*128 + f)*L_ + n0 + p*32 + half*16;
            *(short8*)dst = v0;
            *(short8*)(dst + 8) = v1;
        }
        __syncthreads();
    }
}

// ---------------- fused attention, 64-col blocks: S = au.tanh(aw.t) --------
// grid (64, B, 3). Wave w: a-rows w*64..w*64+63 (4 tiles) x all 64 cols.
// acc1[4][4] = 64 VGPRs (was 128 -> VGPR 196, Occ 11%).
__global__ __launch_bounds__(256) void attn_k(const u16* __restrict__ t_base,
                                              const u16* __restrict__ awf_base,
                                              const u16* __restrict__ auf_base,
                                              u16* __restrict__ S_base){
    __shared__ short sm[16896];   // t-slab 64*136=8704 ; reused as Z 64*264
    const int tid = threadIdx.x, lane = tid & 63;
    const int w = tid >> 6;
    const int q = lane >> 4, lr = lane & 15;
    const int n0 = blockIdx.x * 64;
    const int b  = blockIdx.y;
    const int br = blockIdx.z;
    const u16* tpl = t_base + (size_t)br*PLANE;
    const u16* awf = awf_base + (size_t)br*WFAW_STRIDE;
    const u16* auf = auf_base + (size_t)br*WFAU_STRIDE;
    u16* S = S_base + (size_t)br*SST;

    // stage t: 64 cols x 128 ch
    for (int idx = tid; idx < 1024; idx += 256){
        int col = idx >> 4, g = idx & 15;
        *(short8*)(sm + col*136 + g*8) =
            *(const short8*)(tpl + ((size_t)b*LP_ + POFF + n0 + col)*128 + g*8);
    }
    __syncthreads();

    // phase 1: Z rows w*64.. , cols all 64
    f32x4 acc1[4][4];
    #pragma unroll
    for (int t = 0; t < 4; ++t)
        #pragma unroll
        for (int n = 0; n < 4; ++n) acc1[t][n] = (f32x4){0.f,0.f,0.f,0.f};
    for (int cc = 0; cc < 4; ++cc){
        short8 Af[4];
        const u16* fp = awf + (size_t)(cc*16 + w*4)*512 + lane*8;
        #pragma unroll
        for (int t = 0; t < 4; ++t) Af[t] = *(const short8*)(fp + (size_t)t*512);
        short8 Bf[4];
        #pragma unroll
        for (int n = 0; n < 4; ++n)
            Bf[n] = *(const short8*)(sm + (n*16 + lr)*136 + cc*32 + q*8);
        #pragma unroll
        for (int t = 0; t < 4; ++t)
            #pragma unroll
            for (int n = 0; n < 4; ++n)
                acc1[t][n] = __builtin_amdgcn_mfma_f32_16x16x32_bf16(Af[t], Bf[n], acc1[t][n], 0,0,0);
    }
    __syncthreads();   // t-slab dead

    // Z -> LDS (bf16, [col][arow] stride 264)
    #pragma unroll
    for (int t = 0; t < 4; ++t){
        #pragma unroll
        for (int n = 0; n < 4; ++n){
            int abase = w*64 + t*16 + q*4;
            int cl = n*16 + lr;
            short4v zv;
            #pragma unroll
            for (int r = 0; r < 4; ++r) zv[r] = (short)f2b(tanhf(acc1[t][n][r]));
            *(short4v*)(sm + cl*264 + abase) = zv;
        }
    }
    __syncthreads();

    // phase 2: wave w covers cols w*16..w*16+15
    f32x4 acc2[4];
    #pragma unroll
    for (int t = 0; t < 4; ++t) acc2[t] = (f32x4){0.f,0.f,0.f,0.f};
    for (int cc = 0; cc < 8; ++cc){
        short8 Af2[4];
        const u16* fp2 = auf + (size_t)(cc*4)*512 + lane*8;
        #pragma unroll
        for (int t = 0; t < 4; ++t) Af2[t] = *(const short8*)(fp2 + (size_t)t*512);
        short8 Bf2 = *(const short8*)(sm + (w*16 + lr)*264 + cc*32 + q*8);
        #pragma unroll
        for (int t = 0; t < 4; ++t)
            acc2[t] = __builtin_amdgcn_mfma_f32_16x16x32_bf16(Af2[t], Bf2, acc2[t], 0,0,0);
    }
    #pragma unroll
    for (int t = 0; t < 4; ++t)
        #pragma unroll
        for (int r = 0; r < 4; ++r){
            int c = t*16 + q*4 + r;   // 0..63, padded S
            S[((size_t)b*64 + c)*L_ + n0 + w*16 + lr] = f2b(acc2[t][r]);
        }
}

// ---------------- softmax over L per (br,b,c) bf16 row, in place -----------
__global__ __launch_bounds__(256) void softmax_k(u16* __restrict__ S){
    int c = blockIdx.x, b = blockIdx.y, br = blockIdx.z, t = threadIdx.x;
    u16* p = S + (size_t)br*SST + ((size_t)b*64 + c)*L_;
    __shared__ float sh[256];
    float mx = -1e30f;
    for (int j = t; j < L_; j += 256) mx = fmaxf(mx, b2f(p[j]));
    sh[t] = mx; __syncthreads();
    for (int o = 128; o > 0; o >>= 1){ if (t < o) sh[t] = fmaxf(sh[t], sh[t+o]); __syncthreads(); }
    float m = sh[0]; __syncthreads();
    float sum = 0.f;
    for (int j = t; j < L_; j += 256){ float e = expf(b2f(p[j]) - m); p[j] = f2b(e); sum += e; }
    sh[t] = sum; __syncthreads();
    for (int o = 128; o > 0; o >>= 1){ if (t < o) sh[t] += sh[t+o]; __syncthreads(); }
    float inv = 1.0f / sh[0];
    for (int j = t; j < L_; j += 256) p[j] = f2b(b2f(p[j]) * inv);
}

// ---------------- V-GEMM (branch-fused): 16 chunks of 256 cols -------------
__global__ __launch_bounds__(256) void v_mfma_k(const u16* __restrict__ tT_base,
                                                const u16* __restrict__ S_base,
                                                float* __restrict__ Vp_base){
    int cx = blockIdx.x, b = blockIdx.y, br = blockIdx.z;
    int w = threadIdx.x >> 6, lane = threadIdx.x & 63;
    int q = lane >> 4, lr = lane & 15;
    int l0 = cx*256;
    f32x4 acc[7];
    #pragma unroll
    for (int mt = 0; mt < 7; ++mt) acc[mt] = (f32x4){0.f,0.f,0.f,0.f};
    const u16* tb = tT_base + (size_t)br*TTS + (size_t)b*128*L_;
    const u16* Sb = S_base + (size_t)br*SST + ((size_t)b*64 + w*16 + lr)*L_;
    #pragma unroll
    for (int kk = 0; kk < 8; ++kk){
        int l = l0 + kk*32 + q*8;
        short8 Bf = *(const short8*)(Sb + l);
        #pragma unroll
        for (int mt = 0; mt < 7; ++mt){
            short8 Af = *(const short8*)(tb + (size_t)(mt*16 + lr)*L_ + l);
            acc[mt] = __builtin_amdgcn_mfma_f32_16x16x32_bf16(Af, Bf, acc[mt], 0,0,0);
        }
    }
    int c = w*16 + lr;
    if (c < C_){
        float* vp = Vp_base + (size_t)br*VPS + ((size_t)(b*64 + c)*16 + cx)*112;
        #pragma unroll
        for (int mt = 0; mt < 7; ++mt)
            *(f32x4*)(vp + mt*16 + q*4) = acc[mt];
    }
}

// ---------------- reduce Vpart (all branches) -> ocat ----------------------
__global__ void reduce_v_k(const float* __restrict__ Vp, float* __restrict__ oc){
    int idx = blockIdx.x*256 + threadIdx.x;
    if (idx >= 3*B_*C_*F_) return;
    int f = idx % F_; int rest = idx / F_;
    int c = rest % C_; rest /= C_;
    int b = rest % B_; int br = rest / B_;
    const float* src = Vp + (size_t)br*VPS + ((size_t)(b*64 + c)*16)*112 + f;
    float s = 0.f;
    #pragma unroll
    for (int cx = 0; cx < 16; ++cx) s += src[cx*112];
    oc[((size_t)b*C_ + c)*OC_ + 256 + br*100 + f] = s;
}

// ---------------- GCN ----------------
__global__ void gather_nodes_k(const int* __restrict__ nodes, const float* __restrict__ emb,
                               float* __restrict__ ne){
    int idx = blockIdx.x*256 + threadIdx.x;
    if (idx >= B_*NN_*D_) return;
    int d = idx & 255, n = (idx >> 8) & 511, b = idx >> 17;
    ne[idx] = emb[(size_t)nodes[b*NN_ + n]*D_ + d];
}
__global__ void deg_count_k(const int* __restrict__ edges, int* __restrict__ deg){
    int idx = blockIdx.x*256 + threadIdx.x;
    if (idx >= B_*EE_) return;
    int b = idx >> 13, e = idx & (EE_-1);
    int dst = edges[b*2*EE_ + EE_ + e];
    atomicAdd(&deg[b*NN_ + dst], 1);
}
__global__ void dinv_k(const int* __restrict__ deg, float* __restrict__ dinv){
    int i = blockIdx.x*256 + threadIdx.x;
    if (i < B_*NN_) dinv[i] = 1.0f / sqrtf((float)deg[i]);
}
__global__ void scan_csr_k(const int* __restrict__ deg, int* __restrict__ rp, int* __restrict__ cur){
    int b = blockIdx.x, t = threadIdx.x;    // 512 threads
    __shared__ int sh[NN_];
    int v = deg[b*NN_ + t];
    sh[t] = v; __syncthreads();
    for (int off = 1; off < NN_; off <<= 1){
        int x = (t >= off) ? sh[t-off] : 0;
        __syncthreads();
        sh[t] += x;
        __syncthreads();
    }
    int incl = sh[t], excl = incl - v;
    rp[b*513 + t] = excl;
    cur[b*NN_ + t] = excl;
    if (t == NN_-1) rp[b*513 + NN_] = incl;
}
__global__ void fill_csr_k(const int* __restrict__ edges, int* __restrict__ cur, int* __restrict__ adj){
    int e = blockIdx.x*256 + threadIdx.x, b = blockIdx.y;
    if (e >= ADJ_) return;
    int s, d;
    if (e < EE_){ s = edges[b*2*EE_ + e]; d = edges[b*2*EE_ + EE_ + e]; }
    else        { s = d = e - EE_; }
    int pos = atomicAdd(&cur[b*NN_ + d], 1);
    adj[b*ADJ_ + pos] = s;
}
__global__ __launch_bounds__(256) void gemm_nt_k(const float* __restrict__ A,
                                                 const float* __restrict__ W,
                                                 float* __restrict__ out){
    int b = blockIdx.z, n0 = blockIdx.x*64, i0 = blockIdx.y*64;
    __shared__ float aL[64][17], wL[64][17];
    int tid = threadIdx.x, tx = tid & 15, ty = tid >> 4;
    const float* Ab = A + (size_t)b*NN_*D_;
    float acc[4][4];
    #pragma unroll
    for (int r = 0; r < 4; ++r)
        #pragma unroll
        for (int i = 0; i < 4; ++i) acc[r][i] = 0.f;
    for (int j0 = 0; j0 < D_; j0 += 16){
        for (int idx = tid; idx < 1024; idx += 256){
            int r = idx >> 4, cc = idx & 15;
            aL[r][cc] = Ab[(size_t)(n0+r)*D_ + j0 + cc];
            wL[r][cc] = W[(size_t)(i0+r)*D_ + j0 + cc];
        }
        __syncthreads();
        #pragma unroll
        for (int kk = 0; kk < 16; ++kk){
            float av[4], wv[4];
            #pragma unroll
            for (int r = 0; r < 4; ++r) av[r] = aL[ty*4+r][kk];
            #pragma unroll
            for (int i = 0; i < 4; ++i) wv[i] = wL[tx*4+i][kk];
            #pragma unroll
            for (int r = 0; r < 4; ++r)
                #pragma unroll
                for (int i = 0; i < 4; ++i) acc[r][i] = fmaf(av[r], wv[i], acc[r][i]);
        }
        __syncthreads();
    }
    float* ob = out + (size_t)b*NN_*D_;
    #pragma unroll
    for (int r = 0; r < 4; ++r)
        #pragma unroll
        for (int i = 0; i < 4; ++i)
            ob[(size_t)(n0+ty*4+r)*D_ + i0+tx*4+i] = acc[r][i];
}
__global__ __launch_bounds__(256) void scatter_k(const float* __restrict__ xw,
                                                 const int* __restrict__ adj,
                                                 const int* __restrict__ rp,
                                                 const float* __restrict__ dinv,
                                                 const float* __restrict__ bias,
                                                 float* __restrict__ out,
                                                 int out_bs, int out_ld, int relu){
    int n = blockIdx.x, b = blockIdx.y, t = threadIdx.x;
    const int* rpb = rp + b*513;
    const int* adjb = adj + b*ADJ_;
    const float* xwb = xw + (size_t)b*NN_*D_;
    const float* dvb = dinv + b*NN_;
    int e0 = rpb[n], e1 = rpb[n+1];
    float acc = 0.f;
    for (int e = e0; e < e1; ++e){
        int s = adjb[e];
        acc = fmaf(xwb[(size_t)s*D_ + t], dvb[s], acc);
    }
    float v = fmaf(acc, dvb[n], bias[t]);
    if (relu) v = fmaxf(v, 0.f);
    out[(size_t)b*out_bs + (size_t)n*out_ld + t] = v;
}

// ---------------- fused head ----------------
__global__ __launch_bounds__(128) void final_k(const float* __restrict__ oc,
                                               const float* __restrict__ w1t,
                                               const float* __restrict__ b1,
                                               const float* __restrict__ w2,
                                               const float* __restrict__ b2,
                                               float* __restrict__ y){
    int c = blockIdx.x, b = blockIdx.y, h = threadIdx.x;
    __shared__ float row[OC_];
    __shared__ float red[128];
    const float* src = oc + ((size_t)b*C_ + c)*OC_;
    for (int j = h; j < OC_; j += 128) row[j] = src[j];
    __syncthreads();
    float acc = b1[h];
    #pragma unroll 8
    for (int j = 0; j < OC_; ++j) acc = fmaf(row[j], w1t[j*128 + h], acc);
    float hid = fmaxf(acc, 0.f);
    red[h] = hid * w2[c*128 + h];
    __syncthreads();
    for (int o = 64; o > 0; o >>= 1){ if (h < o) red[h] += red[h+o]; __syncthreads(); }
    if (h == 0) y[b*C_ + c] = red[0] + b2[c];
}

// ===========================================================================
extern "C" void kernel_launch(void* const* d_in, const int* in_sizes, int n_in,
                              void* d_out, int out_size, void* d_ws, size_t ws_size,
                              hipStream_t stream){
    (void)in_sizes; (void)n_in; (void)out_size; (void)ws_size;
    const int*   x          = (const int*)d_in[0];
    const int*   nodes      = (const int*)d_in[2];
    const int*   edges      = (const int*)d_in[3];
    const float* word_emb   = (const float*)d_in[4];
    const float* entity_emb = (const float*)d_in[5];
    const float* bn_gamma   = (const float*)d_in[15];
    const float* bn_beta    = (const float*)d_in[16];
    const float* gc1_w      = (const float*)d_in[19];
    const float* gc1_b      = (const float*)d_in[20];
    const float* gc2_w      = (const float*)d_in[21];
    const float* gc2_b      = (const float*)d_in[22];
    const float* fin1_w     = (const float*)d_in[23];
    const float* fin1_b     = (const float*)d_in[24];
    const float* fin2_w     = (const float*)d_in[25];
    const float* fin2_b     = (const float*)d_in[26];
    float* y = (float*)d_out;

    // ---- workspace layout (~208 MB) ----
    char* base = (char*)d_ws;
    size_t off = 0;
    auto alloc = [&](size_t bytes) -> char* {
        char* p = base + off;
        off += ((bytes + 255) / 256) * 256;
        return p;
    };
    u16* t0 = (u16*)alloc(3*PLANE*2);
    u16* t1 = (u16*)alloc(3*PLANE*2);
    u16* hH = t1;                          // alias: hH (2*PLANE) dead after conv1
    u16* tT = (u16*)alloc(3*TTS*2);
    u16* S  = (u16*)alloc(3*SST*2);        // bf16
    // GCN scratch region, later reused as Vpart (22.0 MB <= 25.2 MB)
    char* G = alloc((size_t)3*B_*NN_*D_*4);
    float* ne = (float*)G;
    float* xw = ne + (size_t)B_*NN_*D_;
    float* g1 = xw + (size_t)B_*NN_*D_;
    float* Vpart = (float*)G;
    float* ocat = (float*)alloc((size_t)B_*C_*OC_*4);
    u16* wfc1  = (u16*)alloc(3*WFC1_STRIDE*2);
    u16* wfres = (u16*)alloc(6*WFRES_STRIDE*2);
    u16* wfaw  = (u16*)alloc(3*WFAW_STRIDE*2);
    u16* wfau  = (u16*)alloc(3*WFAU_STRIDE*2);
    float* w1t   = (float*)alloc((size_t)OC_*128*4);
    float* dinvp = (float*)alloc((size_t)B_*NN_*4);
    int* deg = (int*)alloc((size_t)B_*NN_*4);
    int* rpB = (int*)alloc((size_t)B_*513*4);
    int* cur = (int*)alloc((size_t)B_*NN_*4);
    int* adj = (int*)alloc((size_t)B_*ADJ_*4);

    // ---- init & weight packing ----
    fill_i_k<<<CDIV(B_*NN_,256),256,0,stream>>>(deg, B_*NN_, 1);
    zero_pads3_k<<<CDIV(3*B_*16*128,256),256,0,stream>>>(t0);
    pack_conv1_k<<<dim3(CDIV(9*8*8*512,256),3),256,0,stream>>>(
        (const float*)d_in[6], (const float*)d_in[9], (const float*)d_in[12], wfc1);
    pack_res_k<<<dim3(CDIV(9*4*8*512,256),3,2),256,0,stream>>>(
        (const float*)d_in[8], (const float*)d_in[11], (const float*)d_in[14], wfres);
    pack_aw_k<<<dim3(CDIV(4*16*512,256),3),256,0,stream>>>((const float*)d_in[17], wfaw);
    pack_au_k<<<dim3(CDIV(8*4*512,256),3),256,0,stream>>>((const float*)d_in[18], wfau);

    // ---- embedding (hH lives in the t1 region; t1 pads zeroed after conv1) --
    embed1_k<<<dim3(LP_/8, B_),256,0,stream>>>(x, word_emb, hH);

    // ---- GCN (scratch region G; freed for Vpart afterwards) ----
    gather_nodes_k<<<CDIV(B_*NN_*D_,256),256,0,stream>>>(nodes, entity_emb, ne);
    deg_count_k<<<CDIV(B_*EE_,256),256,0,stream>>>(edges, deg);
    dinv_k<<<CDIV(B_*NN_,256),256,0,stream>>>(deg, dinvp);
    scan_csr_k<<<B_,NN_,0,stream>>>(deg, rpB, cur);
    fill_csr_k<<<dim3(CDIV(ADJ_,256),B_),256,0,stream>>>(edges, cur, adj);
    gemm_nt_k<<<dim3(NN_/64, D_/64, B_),256,0,stream>>>(ne, gc1_w, xw);
    scatter_k<<<dim3(NN_,B_),256,0,stream>>>(xw, adj, rpB, dinvp, gc1_b, g1, NN_*D_, D_, 1);
    gemm_nt_k<<<dim3(NN_/64, D_/64, B_),256,0,stream>>>(g1, gc2_w, xw);
    scatter_k<<<dim3(C_,B_),256,0,stream>>>(xw, adj, rpB, dinvp, gc2_b, ocat, C_*OC_, OC_, 0);

    // ---- encoder: branch-fused dispatches ----
    dim3 gc(64, B_, 3), ga(64, B_, 3);
    // conv1 (all branches): hH -> t0[br]
    conv_mfma_k<0,8><<<gc,256,0,stream>>>(hH, 256, 0,
        wfc1, (long)WFC1_STRIDE,
        (const float*)d_in[7], (const float*)d_in[10], (const float*)d_in[13],
        bn_gamma, bn_beta, 0, t0, nullptr);
    // hH dead; prepare t1 pads (same memory region)
    zero_pads3_k<<<CDIV(3*B_*16*128,256),256,0,stream>>>(t1);
    // res1 (all branches): t0[br] -> t1[br]
    conv_mfma_k<1,4><<<gc,256,0,stream>>>(t0, 128, (long)PLANE,
        wfres, (long)(2*WFRES_STRIDE),
        nullptr, nullptr, nullptr,
        bn_gamma, bn_beta, 100, t1, nullptr);
    // res2 (all branches): t1[br] -> t0[br] + tT[br]
    conv_mfma_k<1,4><<<gc,256,0,stream>>>(t1, 128, (long)PLANE,
        wfres + WFRES_STRIDE, (long)(2*WFRES_STRIDE),
        nullptr, nullptr, nullptr,
        bn_gamma, bn_beta, 200, t0, tT);
    // attention + softmax + V for all branches
    attn_k<<<ga,256,0,stream>>>(t0, wfaw, wfau, S);
    softmax_k<<<dim3(C_,B_,3),256,0,stream>>>(S);
    v_mfma_k<<<dim3(16,B_,3),256,0,stream>>>(tT, S, Vpart);
    reduce_v_k<<<CDIV(3*B_*C_*F_,256),256,0,stream>>>(Vpart, ocat);

    // ---- head ----
    transpose_fin1_k<<<CDIV(OC_*128,256),256,0,stream>>>(fin1_w, w1t);
    final_k<<<dim3(C_,B_),128,0,stream>>>(ocat, w1t, fin1_b, fin2_w, fin2_b, y);
}